// Round 10
// baseline (8180.086 us; speedup 1.0000x reference)
//
#include <hip/hip_runtime.h>

#define HID   1024
#define TLEN  512
#define VOC   128
#define NBLK  256         // 1 block/CU (LDS-bound) -> exactly 32 blocks/XCD
#define NT    4           // teams = XCDs 0..3 (batch-split), XCC-bound
#define NB    32          // blocks per team (column-split, 32 cols each)
#define MR    16          // batch rows per team
#define LDSK  1032        // padded LDS row stride
#define HBUF  (MR * HID)  // one h buffer per team (elements)

typedef __bf16 bf16_t;
typedef __attribute__((ext_vector_type(8))) __bf16 bf16x8;
typedef __attribute__((ext_vector_type(4))) float  f32x4;

// ---- exchange state in STATIC DEVICE GLOBALS (coarse-grained, L2-cached).
// r8's counters proved d_ws is fine-grained/L2-uncached: WRITE_SIZE ~= exact
// h/rh store volume (write-through to MALL) and FETCH ~= per-step h/rh reads
// (L2 misses). Every hop was a MALL round trip (~7us). Statics are cached
// write-back in the XCD's L2; teams are XCC-bound so each team's lines are
// only ever touched by ONE XCD's L2 (replay-safe with write-back).
__device__ __align__(512) bf16_t   g_hring[(size_t)NT * 2 * HBUF];   // 256KB
__device__ __align__(512) bf16_t   g_rh   [(size_t)NT * HBUF];       // 128KB
__device__ __align__(512) bf16_t   g_wz   [(size_t)NT * NB * 32 * HID]; // 8MB
__device__ __align__(512) bf16_t   g_wo   [(size_t)NT * 8 * 16 * HID];  // 1MB
__device__ __align__(512) unsigned g_flags[NT * 256];                // 4KB

__device__ __forceinline__ float sigmoid_fast(float x) {
  return 1.0f / (1.0f + __expf(-x));
}
__device__ __forceinline__ float tanh_fast(float x) {
  float e = __expf(-2.0f * x);
  return (1.0f - e) / (1.0f + e);
}

union PairU { bf16_t b[2]; unsigned u; };

// L1-only invalidate; "memory" clobber orders following loads after it.
__device__ __forceinline__ void l1_inv() {
  asm volatile("buffer_inv" ::: "memory");
}

// Explicit store drain (single-wave __syncthreads may elide its vmcnt(0);
// r8-verified fix for the flag-races-data publish hole).
__device__ __forceinline__ void drain_stores() {
  asm volatile("s_waitcnt vmcnt(0)" ::: "memory");
}

__device__ __forceinline__ bf16x8 ldw(const bf16_t* p) {
  return *reinterpret_cast<const bf16x8*>(p);
}

// r8-proven blocking wait: inv + volatile load per poll iteration. Flag and
// data now live in THIS XCD's L2 (cached statics) -> poll cost ~L2 latency.
__device__ __forceinline__ void wait_flags(const unsigned* f, unsigned tgt) {
  const volatile unsigned* p =
      (const volatile unsigned*)(f + (threadIdx.x & 31));
  for (;;) {
    l1_inv();
    unsigned v = *p;
    if (__all((int)(v - tgt) >= 0)) break;   // wrap-safe compare
  }
}

// publish: barrier + explicit vmcnt(0) drain, then one plain flag store.
__device__ __forceinline__ void publish(unsigned* fw, unsigned v) {
  __syncthreads();
  drain_stores();
  if (threadIdx.x == 0) *(volatile unsigned*)fw = v;
}

#define MFMA(a, b, c) __builtin_amdgcn_mfma_f32_16x16x32_bf16((a), (b), (c), 0, 0, 0)

__global__ void __launch_bounds__(64, 1)
gru_xb(const int* __restrict__ X,
       const float* __restrict__ Wr_x, const float* __restrict__ Wr_h, const float* __restrict__ b_r,
       const float* __restrict__ Wz_x, const float* __restrict__ Wz_h, const float* __restrict__ b_z,
       const float* __restrict__ Wh_x, const float* __restrict__ Wh_h, const float* __restrict__ b_h,
       const float* __restrict__ W_o,  const float* __restrict__ b_o,
       float* __restrict__ out,
       unsigned* __restrict__ ws)      // election/ready state only (memset'd)
{
  __shared__ __align__(16) bf16_t Wbuf[2 * 32 * LDSK];  // Wr + Wh slices, 129KB
  __shared__ __align__(16) float  Obuf[8][16][16];      // out staging, 8KB
  __shared__ int s_team, s_slot;

  // ws layout (words): cnt[x] at 32x (x=0..7) | ready[t] at 512 + 32t
  unsigned* cnt   = ws;
  unsigned* ready = ws + 512;

  const int tid  = threadIdx.x;
  const int n16  = tid & 15;
  const int q    = tid >> 4;

  int bi[4];
#pragma unroll
  for (int i = 0; i < 4; ++i) bi[i] = q * 4 + i;   // local batch rows 0..15

  // ---------- XCC-bound teams: team = XCC_ID (<NT), slot = per-XCD order.
  // 256 blocks at 1/CU => every XCD seats exactly 32 blocks.
  if (tid == 0) {
    unsigned xcc;
    asm volatile("s_getreg_b32 %0, hwreg(HW_REG_XCC_ID)" : "=s"(xcc));
    xcc &= 7u;
    unsigned idx = __hip_atomic_fetch_add(&cnt[xcc * 32], 1u,
        __ATOMIC_RELAXED, __HIP_MEMORY_SCOPE_AGENT);
    s_team = (xcc < NT) ? (int)xcc : -1;
    s_slot = (int)idx;
  }
  __syncthreads();
  const int tau = s_team;
  if (tau < 0) return;                 // XCDs 4..7 exit
  const int s  = s_slot;               // 0..31: column slice owner
  const int c0 = s * 32;

  unsigned* fH = g_flags + tau * 256;
  unsigned* fR = fH + 64;

  if (tid == 0) {                       // replay-safe epoch reset (own L2)
    *(volatile unsigned*)&fH[s] = 0u;
    *(volatile unsigned*)&fR[s] = 0u;
  }

  // ---------- staging (ALL team-private; zero cross-XCD dependencies) ------
  for (int idx = tid; idx < 32 * HID; idx += 64) {
    int n = idx & 31, k = idx >> 5;
    int r = (n & 1) * 16 + (n >> 1);
    Wbuf[r * LDSK + k]             = (bf16_t)Wr_h[k * HID + c0 + n];
    Wbuf[32 * LDSK + r * LDSK + k] = (bf16_t)Wh_h[k * HID + c0 + n];
  }
  bf16_t* wzs = g_wz + (size_t)tau * (NB * 32 * HID) + (size_t)s * (32 * HID);
  for (int idx = tid; idx < 32 * HID; idx += 64) {
    int n = idx & 31, k = idx >> 5;
    int r = (n & 1) * 16 + (n >> 1);
    wzs[r * HID + k] = (bf16_t)Wz_h[k * HID + c0 + n];
  }
  bf16_t* wot = g_wo + (size_t)tau * (8 * 16 * HID);
  if (s < 8) {
    bf16_t* wos = wot + (size_t)s * (16 * HID);
    for (int idx = tid; idx < 16 * HID; idx += 64) {
      int n = idx & 15, k = idx >> 4;
      wos[n * HID + k] = (bf16_t)W_o[k * VOC + s * 16 + n];
    }
  }

  bf16_t* hT  = g_hring + (size_t)tau * (2 * HBUF);
  bf16_t* rhT = g_rh    + (size_t)tau * HBUF;
  const int j0 = c0 + 2 * n16;
#pragma unroll
  for (int i = 0; i < 4; ++i) {
    PairU zz; zz.b[0] = (bf16_t)0.f; zz.b[1] = (bf16_t)0.f;
    *reinterpret_cast<PairU*>(hT + bi[i] * HID + j0) = zz;   // h_0 = 0
  }
  __syncthreads();
  drain_stores();    // flag-zero + staging + h0 stores ALL L2-acked

  // one-time PER-TEAM ready barrier (in memset'd ws): orders every block's
  // flag re-zero + staging before any first poll. ~one MALL round trip.
  if (tid == 0) {
    __hip_atomic_fetch_add(&ready[tau * 32], 1u,
        __ATOMIC_RELAXED, __HIP_MEMORY_SCOPE_AGENT);
    while (__hip_atomic_load(&ready[tau * 32], __ATOMIC_RELAXED,
                             __HIP_MEMORY_SCOPE_AGENT) < (unsigned)NB)
      __builtin_amdgcn_s_sleep(1);
  }
  __syncthreads();
  if (tid == 0) *(volatile unsigned*)&fH[s] = 1u;   // h slot 0 ready

  // ---------- per-step constants ----------
  const float br0 = b_r[j0], br1 = b_r[j0 + 1];
  const float bz0 = b_z[j0], bz1 = b_z[j0 + 1];
  const float bh0 = b_h[j0], bh1 = b_h[j0 + 1];
  const bf16_t* wr0 = &Wbuf[n16 * LDSK + q * 8];
  const bf16_t* wr1 = &Wbuf[(16 + n16) * LDSK + q * 8];
  const bf16_t* wh0 = &Wbuf[32 * LDSK + n16 * LDSK + q * 8];
  const bf16_t* wh1 = &Wbuf[32 * LDSK + (16 + n16) * LDSK + q * 8];
  const bf16_t* wz0 = wzs + n16 * HID + q * 8;
  const bf16_t* wz1 = wzs + (16 + n16) * HID + q * 8;
  const int  aoff  = n16 * HID + q * 8;
  const bf16_t* rhrow = rhT + aoff;

  const bool outw = (s < 8);
  const int  vt   = s;
  const bf16_t* wop = wot + (size_t)vt * (16 * HID) + n16 * HID + q * 8;
  const float bo = outw ? b_o[vt * 16 + n16] : 0.f;
  const int  gb0 = tau * MR;

  f32x4 hm0 = {0.f,0.f,0.f,0.f}, hm1 = {0.f,0.f,0.f,0.f};  // fp32 h master

  for (int t = 0; t < TLEN; ++t) {
    // x-gather prefetch (hides under the hop-A poll)
    float gr0[4], gr1[4], gz0[4], gz1[4], gh0[4], gh1[4];
#pragma unroll
    for (int i = 0; i < 4; ++i) {
      int xb = X[(gb0 + bi[i]) * TLEN + t];
      gr0[i] = Wr_x[xb * HID + j0]; gr1[i] = Wr_x[xb * HID + j0 + 1];
      gz0[i] = Wz_x[xb * HID + j0]; gz1[i] = Wz_x[xb * HID + j0 + 1];
      gh0[i] = Wh_x[xb * HID + j0]; gh1[i] = Wh_x[xb * HID + j0 + 1];
    }

    // ---- hop A: h_t ready ----
    wait_flags(fH, (unsigned)(t + 1));
    const bf16_t* hrow = hT + (t & 1) * HBUF + aoff;
    bf16x8 areg[32];
#pragma unroll
    for (int kk = 0; kk < 32; ++kk) areg[kk] = ldw(hrow + kk * 32);

    // ---- r phase (critical; 4 independent MFMA chains) ----
    f32x4 aR0 = {0.f,0.f,0.f,0.f}, aR1 = {0.f,0.f,0.f,0.f};
    f32x4 bR0 = {0.f,0.f,0.f,0.f}, bR1 = {0.f,0.f,0.f,0.f};
#pragma unroll
    for (int kk = 0; kk < 16; ++kk) {
      aR0 = MFMA(areg[kk],      ldw(wr0 + kk * 32),        aR0);
      aR1 = MFMA(areg[kk],      ldw(wr1 + kk * 32),        aR1);
      bR0 = MFMA(areg[kk + 16], ldw(wr0 + (kk + 16) * 32), bR0);
      bR1 = MFMA(areg[kk + 16], ldw(wr1 + (kk + 16) * 32), bR1);
    }
    aR0 += bR0; aR1 += bR1;
#pragma unroll
    for (int i = 0; i < 4; ++i) {
      float r0 = sigmoid_fast(aR0[i] + br0 + gr0[i]);
      float r1 = sigmoid_fast(aR1[i] + br1 + gr1[i]);
      PairU c;
      c.b[0] = (bf16_t)(r0 * hm0[i]);   // fp32 register master (== h_t)
      c.b[1] = (bf16_t)(r1 * hm1[i]);
      *reinterpret_cast<PairU*>(rhT + bi[i] * HID + j0) = c;
    }
    publish(&fR[s], (unsigned)(t + 1));

    // ---- out[t-1] = h_t @ W_o into LDS staging (shadow) ----
    if (outw && t) {
      f32x4 oa = {0.f,0.f,0.f,0.f}, ob2 = {0.f,0.f,0.f,0.f};
#pragma unroll
      for (int kk = 0; kk < 16; ++kk) {
        oa  = MFMA(areg[kk],      ldw(wop + kk * 32),        oa);
        ob2 = MFMA(areg[kk + 16], ldw(wop + (kk + 16) * 32), ob2);
      }
      oa += ob2;
      const int oi = (t - 1) & 7;
#pragma unroll
      for (int i = 0; i < 4; ++i) Obuf[oi][bi[i]][n16] = oa[i] + bo;
    }

    // ---- z phase (shadow; reuses areg, streams wz from local L2) ----
    f32x4 aZ0 = {0.f,0.f,0.f,0.f}, aZ1 = {0.f,0.f,0.f,0.f};
    f32x4 bZ0 = {0.f,0.f,0.f,0.f}, bZ1 = {0.f,0.f,0.f,0.f};
#pragma unroll
    for (int kk = 0; kk < 16; ++kk) {
      aZ0 = MFMA(areg[kk],      ldw(wz0 + kk * 32),        aZ0);
      aZ1 = MFMA(areg[kk],      ldw(wz1 + kk * 32),        aZ1);
      bZ0 = MFMA(areg[kk + 16], ldw(wz0 + (kk + 16) * 32), bZ0);
      bZ1 = MFMA(areg[kk + 16], ldw(wz1 + (kk + 16) * 32), bZ1);
    }
    aZ0 += bZ0; aZ1 += bZ1;
    f32x4 z0, z1;
#pragma unroll
    for (int i = 0; i < 4; ++i) {
      z0[i] = sigmoid_fast(aZ0[i] + bz0 + gz0[i]);
      z1[i] = sigmoid_fast(aZ1[i] + bz1 + gz1[i]);
    }

    // ---- hop B: rh ready; h_tilde phase (critical) ----
    wait_flags(fR, (unsigned)(t + 1));
    bf16x8 breg[32];
#pragma unroll
    for (int kk = 0; kk < 32; ++kk) breg[kk] = ldw(rhrow + kk * 32);
    f32x4 aH0 = {0.f,0.f,0.f,0.f}, aH1 = {0.f,0.f,0.f,0.f};
    f32x4 bH0 = {0.f,0.f,0.f,0.f}, bH1 = {0.f,0.f,0.f,0.f};
#pragma unroll
    for (int kk = 0; kk < 16; ++kk) {
      aH0 = MFMA(breg[kk],      ldw(wh0 + kk * 32),        aH0);
      aH1 = MFMA(breg[kk],      ldw(wh1 + kk * 32),        aH1);
      bH0 = MFMA(breg[kk + 16], ldw(wh0 + (kk + 16) * 32), bH0);
      bH1 = MFMA(breg[kk + 16], ldw(wh1 + (kk + 16) * 32), bH1);
    }
    aH0 += bH0; aH1 += bH1;
    bf16_t* hnext = hT + ((t + 1) & 1) * HBUF;
#pragma unroll
    for (int i = 0; i < 4; ++i) {
      float ht0 = tanh_fast(aH0[i] + bh0 + gh0[i]);
      float ht1 = tanh_fast(aH1[i] + bh1 + gh1[i]);
      float hn0 = z0[i] * hm0[i] + (1.f - z0[i]) * ht0;
      float hn1 = z1[i] * hm1[i] + (1.f - z1[i]) * ht1;
      hm0[i] = hn0; hm1[i] = hn1;
      PairU c; c.b[0] = (bf16_t)hn0; c.b[1] = (bf16_t)hn1;
      *reinterpret_cast<PairU*>(hnext + bi[i] * HID + j0) = c;
    }
    publish(&fH[s], (unsigned)(t + 2));

    // ---- out flush AFTER publish: scattered store acks drain during the
    // next hop-A wait, not inside a publish drain.
    if (outw && t && ((t - 1) & 7) == 7) {
      const int rb = t - 8;
#pragma unroll
      for (int m = 0; m < 32; ++m) {
        int e = m * 64 + tid;
        int row = e >> 7, tt = (e >> 4) & 7, cc = e & 15;
        out[((gb0 + row) * TLEN + rb + tt) * VOC + vt * 16 + cc] =
            Obuf[tt][row][cc];
      }
    }
  }

  // ---- epilogue: out[TLEN-1] = h_TLEN @ W_o, flush rows 504..511 ----
  if (outw) {
    wait_flags(fH, (unsigned)(TLEN + 1));
    const bf16_t* hrow = hT + (TLEN & 1) * HBUF + aoff;
    bf16x8 areg[32];
#pragma unroll
    for (int kk = 0; kk < 32; ++kk) areg[kk] = ldw(hrow + kk * 32);
    f32x4 oa = {0.f,0.f,0.f,0.f}, ob2 = {0.f,0.f,0.f,0.f};
#pragma unroll
    for (int kk = 0; kk < 16; ++kk) {
      oa  = MFMA(areg[kk],      ldw(wop + kk * 32),        oa);
      ob2 = MFMA(areg[kk + 16], ldw(wop + (kk + 16) * 32), ob2);
    }
    oa += ob2;
#pragma unroll
    for (int i = 0; i < 4; ++i) Obuf[7][bi[i]][n16] = oa[i] + bo;
    __syncthreads();   // cross-lane Obuf visibility before the flush
#pragma unroll
    for (int m = 0; m < 32; ++m) {
      int e = m * 64 + tid;
      int row = e >> 7, tt = (e >> 4) & 7, cc = e & 15;
      out[((gb0 + row) * TLEN + 504 + tt) * VOC + vt * 16 + cc] =
          Obuf[tt][row][cc];
    }
  }

  // order dirty state for the next replay (same XCD reuses same lines, so
  // L2-local coherence suffices; fence is belt-and-suspenders)
  __builtin_amdgcn_fence(__ATOMIC_RELEASE, "agent");
}

extern "C" void kernel_launch(void* const* d_in, const int* in_sizes, int n_in,
                              void* d_out, int out_size, void* d_ws, size_t ws_size,
                              hipStream_t stream) {
  const int*   X    = (const int*)d_in[0];
  const float* Wr_x = (const float*)d_in[1];
  const float* Wr_h = (const float*)d_in[2];
  const float* b_r  = (const float*)d_in[3];
  const float* Wz_x = (const float*)d_in[4];
  const float* Wz_h = (const float*)d_in[5];
  const float* b_z  = (const float*)d_in[6];
  const float* Wh_x = (const float*)d_in[7];
  const float* Wh_h = (const float*)d_in[8];
  const float* b_h  = (const float*)d_in[9];
  const float* W_o  = (const float*)d_in[10];
  const float* b_o  = (const float*)d_in[11];

  // ws: election counters + per-team ready barriers only (4KB, zeroed)
  hipMemsetAsync(d_ws, 0, 4096, stream);

  gru_xb<<<NBLK, 64, 0, stream>>>(
      X, Wr_x, Wr_h, b_r, Wz_x, Wz_h, b_z, Wh_x, Wh_h, b_h, W_o, b_o,
      (float*)d_out, (unsigned*)d_ws);
}

// Round 12
// 7810.258 us; speedup vs baseline: 1.0474x; 1.0474x over previous
//
#include <hip/hip_runtime.h>

#define HID   1024
#define TLEN  512
#define VOC   128
#define NBLK  256         // 1 block/CU (LDS-bound) -> exactly 32 blocks/XCD
#define NT    4           // independent teams (batch-split), one per XCD
#define NB    32          // blocks per team (column-split, 32 cols each)
#define MR    16          // batch rows per team
#define LDSK  1032        // padded LDS row stride
#define HBUF  (MR * HID)  // one h buffer per team (elements)

typedef __bf16 bf16_t;
typedef __attribute__((ext_vector_type(8))) __bf16 bf16x8;
typedef __attribute__((ext_vector_type(4))) float  f32x4;

__device__ __forceinline__ float sigmoid_fast(float x) {
  return 1.0f / (1.0f + __expf(-x));
}
__device__ __forceinline__ float tanh_fast(float x) {
  float e = __expf(-2.0f * x);
  return (1.0f - e) / (1.0f + e);
}

union PairU { bf16_t b[2]; unsigned u; };

// L1-only invalidate; "memory" clobber orders following loads after it.
// SESSION LESSON: the ONLY consume sequence that passes on this part is
// inv-BEFORE-flag-load on every poll iteration (r4/r8). Observing the flag
// first and invalidating after (r5/r6/r7/r9/r11) fails with one-step-stale
// data every time. Do not "optimize" this wait.
__device__ __forceinline__ void l1_inv() {
  asm volatile("buffer_inv" ::: "memory");
}

// Explicit store drain. __syncthreads() in a SINGLE-WAVE block may drop its
// vmcnt(0) (no other waves observe the fence) — then the flag store races
// the data stores to L2/MALL. r5-r7 bug; fix verified in r8.
__device__ __forceinline__ void drain_stores() {
  asm volatile("s_waitcnt vmcnt(0)" ::: "memory");
}

__device__ __forceinline__ bf16x8 ldw(const bf16_t* p) {
  return *reinterpret_cast<const bf16x8*>(p);
}

// r4/r8-proven blocking wait: inv + volatile load per poll iteration. Data
// loads that follow the break are ordered after the last inv (asm memory
// clobber) and re-fetch from L2/MALL.
__device__ __forceinline__ void wait_flags(const unsigned* f, unsigned tgt) {
  const volatile unsigned* p =
      (const volatile unsigned*)(f + (threadIdx.x & 31));
  for (;;) {
    l1_inv();
    unsigned v = *p;
    if (__all((int)(v - tgt) >= 0)) break;   // wrap-safe compare
  }
}

// publish: barrier + EXPLICIT vmcnt(0) drain, then one plain flag store.
__device__ __forceinline__ void publish(unsigned* fw, unsigned v) {
  __syncthreads();
  drain_stores();
  if (threadIdx.x == 0) *(volatile unsigned*)fw = v;
}

#define MFMA(a, b, c) __builtin_amdgcn_mfma_f32_16x16x32_bf16((a), (b), (c), 0, 0, 0)

__global__ void __launch_bounds__(64, 1)
gru_mt2(const int* __restrict__ X,
        const float* __restrict__ Wr_x, const float* __restrict__ Wr_h, const float* __restrict__ b_r,
        const float* __restrict__ Wz_x, const float* __restrict__ Wz_h, const float* __restrict__ b_z,
        const float* __restrict__ Wh_x, const float* __restrict__ Wh_h, const float* __restrict__ b_h,
        const float* __restrict__ W_o,  const float* __restrict__ b_o,
        float* __restrict__ out,
        bf16_t* __restrict__ hring, bf16_t* __restrict__ rh_bf,
        bf16_t* __restrict__ wz_bf, bf16_t* __restrict__ wo_bf,
        unsigned* __restrict__ flags)
{
  __shared__ __align__(16) bf16_t Wbuf[2 * 32 * LDSK];  // Wr + Wh slices, 129KB
  __shared__ __align__(16) float  Obuf[8][16][16];      // out staging, 8KB
  __shared__ int s_team, s_slot;

  // flag-space layout (words; first 16KB of ws memset to 0 each launch):
  //   team t: fH = flags + 256t (+0..31), fR = fH + 64
  //   cnt[x] at 1024+32x | tcnt at 1536 | xteam[x] at 2048+32x | ready at 3072
  unsigned* cnt   = flags + 1024;
  unsigned* tcnt  = flags + 1536;
  unsigned* xteam = flags + 2048;
  unsigned* ready = flags + 3072;

  const int tid  = threadIdx.x;
  const int n16  = tid & 15;
  const int q    = tid >> 4;

  int bi[4];
#pragma unroll
  for (int i = 0; i < 4; ++i) bi[i] = q * 4 + i;   // local batch rows 0..15

  // ---------- self-organize: every XCD seats exactly 32 blocks; the 32nd
  // block claims a team id; first NT XCDs win, losers exit.
  if (tid == 0) {
    unsigned xcc;
    asm volatile("s_getreg_b32 %0, hwreg(HW_REG_XCC_ID)" : "=s"(xcc));
    xcc &= 7u;
    unsigned idx = __hip_atomic_fetch_add(&cnt[xcc * 32], 1u,
        __ATOMIC_RELAXED, __HIP_MEMORY_SCOPE_AGENT);
    if (idx == NB - 1) {
      unsigned tcl = __hip_atomic_fetch_add(tcnt, 1u,
          __ATOMIC_RELAXED, __HIP_MEMORY_SCOPE_AGENT);
      __hip_atomic_store(&xteam[xcc * 32], (tcl < NT) ? (tcl + 1u) : 0xFFu,
          __ATOMIC_RELAXED, __HIP_MEMORY_SCOPE_AGENT);
    }
    unsigned v;
    do {
      v = __hip_atomic_load(&xteam[xcc * 32], __ATOMIC_RELAXED,
                            __HIP_MEMORY_SCOPE_AGENT);
      __builtin_amdgcn_s_sleep(1);
    } while (v == 0u);
    s_team = (v == 0xFFu) ? -1 : (int)(v - 1u);
    s_slot = (int)idx;
  }
  __syncthreads();
  const int tau = s_team;
  if (tau < 0) return;
  const int s  = s_slot;               // 0..31: column slice owner
  const int c0 = s * 32;

  unsigned* fH = flags + tau * 256;
  unsigned* fR = fH + 64;

  if (tid == 0) {                       // replay-safe epoch reset (in-L2)
    *(volatile unsigned*)&fH[s] = 0u;
    *(volatile unsigned*)&fR[s] = 0u;
  }

  // ---------- staging ----------
  for (int idx = tid; idx < 32 * HID; idx += 64) {
    int n = idx & 31, k = idx >> 5;
    int r = (n & 1) * 16 + (n >> 1);
    Wbuf[r * LDSK + k]             = (bf16_t)Wr_h[k * HID + c0 + n];
    Wbuf[32 * LDSK + r * LDSK + k] = (bf16_t)Wh_h[k * HID + c0 + n];
  }
  bf16_t* wzs = wz_bf + s * (32 * HID);
  if (tau == 0) {
    for (int idx = tid; idx < 32 * HID; idx += 64) {
      int n = idx & 31, k = idx >> 5;
      int r = (n & 1) * 16 + (n >> 1);
      wzs[r * HID + k] = (bf16_t)Wz_h[k * HID + c0 + n];
    }
    if (s < 8) {
      bf16_t* wos = wo_bf + s * (16 * HID);
      for (int idx = tid; idx < 16 * HID; idx += 64) {
        int n = idx & 15, k = idx >> 4;
        wos[n * HID + k] = (bf16_t)W_o[k * VOC + s * 16 + n];
      }
    }
  }

  bf16_t* hT  = hring + tau * (2 * HBUF);
  bf16_t* rhT = rh_bf + tau * HBUF;
  const int j0 = c0 + 2 * n16;
#pragma unroll
  for (int i = 0; i < 4; ++i) {
    PairU zz; zz.b[0] = (bf16_t)0.f; zz.b[1] = (bf16_t)0.f;
    *reinterpret_cast<PairU*>(hT + bi[i] * HID + j0) = zz;   // h_0 = 0
  }
  __syncthreads();
  drain_stores();    // flag-zero + staging + h0 stores ALL visible in L2

  if (tid == 0) {    // one-time global ready barrier (orders staging globally)
    __hip_atomic_fetch_add(ready, 1u, __ATOMIC_RELAXED, __HIP_MEMORY_SCOPE_AGENT);
    while (__hip_atomic_load(ready, __ATOMIC_RELAXED, __HIP_MEMORY_SCOPE_AGENT)
           < (unsigned)(NT * NB))
      __builtin_amdgcn_s_sleep(1);
  }
  __syncthreads();
  if (tid == 0) *(volatile unsigned*)&fH[s] = 1u;   // h slot 0 ready

  // ---------- per-step constants ----------
  const float br0 = b_r[j0], br1 = b_r[j0 + 1];
  const float bz0 = b_z[j0], bz1 = b_z[j0 + 1];
  const float bh0 = b_h[j0], bh1 = b_h[j0 + 1];
  const bf16_t* wr0 = &Wbuf[n16 * LDSK + q * 8];
  const bf16_t* wr1 = &Wbuf[(16 + n16) * LDSK + q * 8];
  const bf16_t* wh0 = &Wbuf[32 * LDSK + n16 * LDSK + q * 8];
  const bf16_t* wh1 = &Wbuf[32 * LDSK + (16 + n16) * LDSK + q * 8];
  const bf16_t* wz0 = wzs + n16 * HID + q * 8;
  const bf16_t* wz1 = wzs + (16 + n16) * HID + q * 8;
  const int  aoff  = n16 * HID + q * 8;
  const bf16_t* rhrow = rhT + aoff;

  const bool outw = (s < 8);
  const int  vt   = s;
  const bf16_t* wop = wo_bf + vt * (16 * HID) + n16 * HID + q * 8;
  const float bo = outw ? b_o[vt * 16 + n16] : 0.f;
  const int  gb0 = tau * MR;

  f32x4 hm0 = {0.f,0.f,0.f,0.f}, hm1 = {0.f,0.f,0.f,0.f};  // fp32 h master

  for (int t = 0; t < TLEN; ++t) {
    // x-gather prefetch (hides under the hop-A poll)
    float gr0[4], gr1[4], gz0[4], gz1[4], gh0[4], gh1[4];
#pragma unroll
    for (int i = 0; i < 4; ++i) {
      int xb = X[(gb0 + bi[i]) * TLEN + t];
      gr0[i] = Wr_x[xb * HID + j0]; gr1[i] = Wr_x[xb * HID + j0 + 1];
      gz0[i] = Wz_x[xb * HID + j0]; gz1[i] = Wz_x[xb * HID + j0 + 1];
      gh0[i] = Wh_x[xb * HID + j0]; gh1[i] = Wh_x[xb * HID + j0 + 1];
    }

    // ---- hop A: h_t ready ----
    wait_flags(fH, (unsigned)(t + 1));
    const bf16_t* hrow = hT + (t & 1) * HBUF + aoff;
    bf16x8 areg[32];
#pragma unroll
    for (int kk = 0; kk < 32; ++kk) areg[kk] = ldw(hrow + kk * 32);

    // ---- r phase (critical; 4 independent MFMA chains) ----
    f32x4 aR0 = {0.f,0.f,0.f,0.f}, aR1 = {0.f,0.f,0.f,0.f};
    f32x4 bR0 = {0.f,0.f,0.f,0.f}, bR1 = {0.f,0.f,0.f,0.f};
#pragma unroll
    for (int kk = 0; kk < 16; ++kk) {
      aR0 = MFMA(areg[kk],      ldw(wr0 + kk * 32),        aR0);
      aR1 = MFMA(areg[kk],      ldw(wr1 + kk * 32),        aR1);
      bR0 = MFMA(areg[kk + 16], ldw(wr0 + (kk + 16) * 32), bR0);
      bR1 = MFMA(areg[kk + 16], ldw(wr1 + (kk + 16) * 32), bR1);
    }
    aR0 += bR0; aR1 += bR1;
#pragma unroll
    for (int i = 0; i < 4; ++i) {
      float r0 = sigmoid_fast(aR0[i] + br0 + gr0[i]);
      float r1 = sigmoid_fast(aR1[i] + br1 + gr1[i]);
      PairU c;
      c.b[0] = (bf16_t)(r0 * hm0[i]);   // fp32 register master (== h_t)
      c.b[1] = (bf16_t)(r1 * hm1[i]);
      *reinterpret_cast<PairU*>(rhT + bi[i] * HID + j0) = c;
    }
    publish(&fR[s], (unsigned)(t + 1));

    // ---- out[t-1] = h_t @ W_o into LDS staging (shadow) ----
    if (outw && t) {
      f32x4 oa = {0.f,0.f,0.f,0.f}, ob2 = {0.f,0.f,0.f,0.f};
#pragma unroll
      for (int kk = 0; kk < 16; ++kk) {
        oa  = MFMA(areg[kk],      ldw(wop + kk * 32),        oa);
        ob2 = MFMA(areg[kk + 16], ldw(wop + (kk + 16) * 32), ob2);
      }
      oa += ob2;
      const int oi = (t - 1) & 7;
#pragma unroll
      for (int i = 0; i < 4; ++i) Obuf[oi][bi[i]][n16] = oa[i] + bo;
    }

    // ---- z phase (shadow; reuses areg, streams wz from local L2) ----
    f32x4 aZ0 = {0.f,0.f,0.f,0.f}, aZ1 = {0.f,0.f,0.f,0.f};
    f32x4 bZ0 = {0.f,0.f,0.f,0.f}, bZ1 = {0.f,0.f,0.f,0.f};
#pragma unroll
    for (int kk = 0; kk < 16; ++kk) {
      aZ0 = MFMA(areg[kk],      ldw(wz0 + kk * 32),        aZ0);
      aZ1 = MFMA(areg[kk],      ldw(wz1 + kk * 32),        aZ1);
      bZ0 = MFMA(areg[kk + 16], ldw(wz0 + (kk + 16) * 32), bZ0);
      bZ1 = MFMA(areg[kk + 16], ldw(wz1 + (kk + 16) * 32), bZ1);
    }
    aZ0 += bZ0; aZ1 += bZ1;
    f32x4 z0, z1;
#pragma unroll
    for (int i = 0; i < 4; ++i) {
      z0[i] = sigmoid_fast(aZ0[i] + bz0 + gz0[i]);
      z1[i] = sigmoid_fast(aZ1[i] + bz1 + gz1[i]);
    }

    // ---- hop B: rh ready; h_tilde phase (critical) ----
    wait_flags(fR, (unsigned)(t + 1));
    bf16x8 breg[32];
#pragma unroll
    for (int kk = 0; kk < 32; ++kk) breg[kk] = ldw(rhrow + kk * 32);
    f32x4 aH0 = {0.f,0.f,0.f,0.f}, aH1 = {0.f,0.f,0.f,0.f};
    f32x4 bH0 = {0.f,0.f,0.f,0.f}, bH1 = {0.f,0.f,0.f,0.f};
#pragma unroll
    for (int kk = 0; kk < 16; ++kk) {
      aH0 = MFMA(breg[kk],      ldw(wh0 + kk * 32),        aH0);
      aH1 = MFMA(breg[kk],      ldw(wh1 + kk * 32),        aH1);
      bH0 = MFMA(breg[kk + 16], ldw(wh0 + (kk + 16) * 32), bH0);
      bH1 = MFMA(breg[kk + 16], ldw(wh1 + (kk + 16) * 32), bH1);
    }
    aH0 += bH0; aH1 += bH1;
    bf16_t* hnext = hT + ((t + 1) & 1) * HBUF;
#pragma unroll
    for (int i = 0; i < 4; ++i) {
      float ht0 = tanh_fast(aH0[i] + bh0 + gh0[i]);
      float ht1 = tanh_fast(aH1[i] + bh1 + gh1[i]);
      float hn0 = z0[i] * hm0[i] + (1.f - z0[i]) * ht0;
      float hn1 = z1[i] * hm1[i] + (1.f - z1[i]) * ht1;
      hm0[i] = hn0; hm1[i] = hn1;
      PairU c; c.b[0] = (bf16_t)hn0; c.b[1] = (bf16_t)hn1;
      *reinterpret_cast<PairU*>(hnext + bi[i] * HID + j0) = c;
    }
    publish(&fH[s], (unsigned)(t + 2));

    // ---- out flush AFTER publish: the 8 out-blocks' scattered HBM store
    // acks drain during the next hop-A wait, not inside a publish drain.
    if (outw && t && ((t - 1) & 7) == 7) {
      const int rb = t - 8;
#pragma unroll
      for (int m = 0; m < 32; ++m) {
        int e = m * 64 + tid;
        int row = e >> 7, tt = (e >> 4) & 7, cc = e & 15;
        out[((gb0 + row) * TLEN + rb + tt) * VOC + vt * 16 + cc] =
            Obuf[tt][row][cc];
      }
    }
  }

  // ---- epilogue: out[TLEN-1] = h_TLEN @ W_o, flush rows 504..511 ----
  if (outw) {
    wait_flags(fH, (unsigned)(TLEN + 1));
    const bf16_t* hrow = hT + (TLEN & 1) * HBUF + aoff;
    bf16x8 areg[32];
#pragma unroll
    for (int kk = 0; kk < 32; ++kk) areg[kk] = ldw(hrow + kk * 32);
    f32x4 oa = {0.f,0.f,0.f,0.f}, ob2 = {0.f,0.f,0.f,0.f};
#pragma unroll
    for (int kk = 0; kk < 16; ++kk) {
      oa  = MFMA(areg[kk],      ldw(wop + kk * 32),        oa);
      ob2 = MFMA(areg[kk + 16], ldw(wop + (kk + 16) * 32), ob2);
    }
    oa += ob2;
#pragma unroll
    for (int i = 0; i < 4; ++i) Obuf[7][bi[i]][n16] = oa[i] + bo;
    __syncthreads();   // cross-lane Obuf visibility before the flush
#pragma unroll
    for (int m = 0; m < 32; ++m) {
      int e = m * 64 + tid;
      int row = e >> 7, tt = (e >> 4) & 7, cc = e & 15;
      out[((gb0 + row) * TLEN + 504 + tt) * VOC + vt * 16 + cc] =
          Obuf[tt][row][cc];
    }
  }

  // write back/order dirty state for the next replay
  __builtin_amdgcn_fence(__ATOMIC_RELEASE, "agent");
}

extern "C" void kernel_launch(void* const* d_in, const int* in_sizes, int n_in,
                              void* d_out, int out_size, void* d_ws, size_t ws_size,
                              hipStream_t stream) {
  const int*   X    = (const int*)d_in[0];
  const float* Wr_x = (const float*)d_in[1];
  const float* Wr_h = (const float*)d_in[2];
  const float* b_r  = (const float*)d_in[3];
  const float* Wz_x = (const float*)d_in[4];
  const float* Wz_h = (const float*)d_in[5];
  const float* b_z  = (const float*)d_in[6];
  const float* Wh_x = (const float*)d_in[7];
  const float* Wh_h = (const float*)d_in[8];
  const float* b_h  = (const float*)d_in[9];
  const float* W_o  = (const float*)d_in[10];
  const float* b_o  = (const float*)d_in[11];

  char* ws = (char*)d_ws;
  // layout: [flags 16KB | hring 4x2x32KB | rh 4x32KB | wz 2MB | wo 256KB]
  unsigned* flags = (unsigned*)ws;
  bf16_t*   hring = (bf16_t*)(ws + 16384);
  bf16_t*   rh_bf = (bf16_t*)(ws + 16384 + (size_t)NT * 2 * HBUF * sizeof(bf16_t));
  bf16_t*   wz_bf = (bf16_t*)(ws + 16384 + (size_t)NT * 3 * HBUF * sizeof(bf16_t));
  bf16_t*   wo_bf = (bf16_t*)(ws + 16384 + (size_t)NT * 3 * HBUF * sizeof(bf16_t)
                              + (size_t)NB * 32 * HID * sizeof(bf16_t));

  hipMemsetAsync(ws, 0, 16384, stream);

  gru_mt2<<<NBLK, 64, 0, stream>>>(
      X, Wr_x, Wr_h, b_r, Wz_x, Wz_h, b_z, Wh_x, Wh_h, b_h, W_o, b_o,
      (float*)d_out, hring, rh_bf, wz_bf, wo_bf, flags);
}